// Round 5
// baseline (445.342 us; speedup 1.0000x reference)
//
#include <hip/hip_runtime.h>
#include <hip/hip_bf16.h>
#include <hip/hip_cooperative_groups.h>
#include <stdint.h>

namespace cg = cooperative_groups;

// RecursiveDecoder, single cooperative kernel. M=128, H=F=256, T=4, ITERS=2, NSEM=57.
// Stages (grid.sync between each):
//  S0 cf0 = relu(pf @ W_parent + b)                 [37 MB weight read, HBM-bound]
//  S1 A,B = cf0@W_el halves; P,Q = cf0@Wne0[0:512]; exists logits; pack W3T bf16
//  S2 EL = relu(A[i]+B[j]+bel) -> ELbf (bf16, XOR-swizzled); edge logits (fp32)
//  S3 kf(it0): R-tile = ELbf@W3 via MFMA, fused masked scatter-max -> cf1  (R never materialized)
//  S4 P,Q = cf1@Wne1[0:512]
//  S5 kf(it1) -> cf2
//  S6 h = relu([cf0|cf1|cf2]@W_child + bc)
//  S7 out_co = relu(h@W_child2+b2); sem = h@W_sem+bsem
// Mask-critical values (exists/edge logits) stay fp32; only EL->R path is bf16 MFMA.
// ws: cf0 0 | cf1 128K | cf2 256K | A 384K | B 512K | P 640K | Q 768K | ex0 896K |
//     hws 917504 | W3T 1048576 (256K) | ELbf 2097152 (8M)

typedef unsigned short ushort_t;
using f32x4 = __attribute__((ext_vector_type(4))) float;
using s16x8 = __attribute__((ext_vector_type(8))) short;

struct KParams {
  const float *p0, *p1, *p2, *Wp, *bp, *Wex, *bex, *Wsm, *bsm, *Wel, *bel,
              *Wee, *bee, *Wne, *bne, *Wc, *bc, *W2, *b2;
  float *out;
  float *cf0, *cf1, *cf2, *A, *B, *P, *Q, *ex0, *hws;
  ushort_t *W3T, *ELbf;
};

__device__ __forceinline__ ushort_t f2bf(float x) {
  __hip_bfloat16 h = __float2bfloat16(x);
  return *reinterpret_cast<ushort_t*>(&h);
}

// Fused GEMM(128x256 @ 256x128) + masked scatter-max. Block (i, nh). One 128x128
// C-tile per block; acc never leaves registers; epilogue does max over (j,t) mask.
__device__ void kf_stage(const KParams& p, const ushort_t* W3T_it,
                         const float* Wne_it, float* cfn, char* smem,
                         int bid, int tid) {
  int i = bid >> 1, nh = bid & 1;
  if (p.ex0[i] == 0.f) {                       // block-uniform
    if (tid < 128) cfn[i * 256 + nh * 128 + tid] = 0.f;
    return;
  }
  ushort_t* lA = (ushort_t*)smem;              // 16 KB
  ushort_t* lB = (ushort_t*)(smem + 16384);    // 16 KB
  float* sl = (float*)(smem + 32768);          // 512 f (edge logits row i)
  float* se = (float*)(smem + 34816);          // 128 f (exists mask)
  float* red = (float*)(smem + 35328);         // 256 f
  sl[tid] = p.out[40192 + i * 512 + tid];
  sl[256 + tid] = p.out[40192 + i * 512 + 256 + tid];
  if (tid < 128) se[tid] = p.ex0[tid];
  int lane = tid & 63, wid = tid >> 6;
  int wr = wid >> 1, wc = wid & 1;
  f32x4 acc[4][4] = {};
  for (int ks = 0; ks < 256; ks += 64) {
    __syncthreads();
    #pragma unroll
    for (int rr = 0; rr < 4; ++rr) {
      int c = rr * 4 + wid;                    // wave-uniform chunk 0..15
      int row = c * 8 + (lane >> 3);
      int co = (lane & 7) * 8;
      const ushort_t* sa = p.ELbf + (size_t)(i * 128 + row) * 256 + ks + co;
      const ushort_t* sb = W3T_it + (size_t)(nh * 128 + row) * 256 + ks + co;
      __builtin_amdgcn_global_load_lds((const __attribute__((address_space(1))) void*)sa,
                                       (__attribute__((address_space(3))) void*)(lA + c * 512), 16, 0, 0);
      __builtin_amdgcn_global_load_lds((const __attribute__((address_space(1))) void*)sb,
                                       (__attribute__((address_space(3))) void*)(lB + c * 512), 16, 0, 0);
    }
    __syncthreads();
    #pragma unroll
    for (int kk = 0; kk < 2; ++kk) {
      s16x8 af[4], bfr[4];
      #pragma unroll
      for (int mt = 0; mt < 4; ++mt) {
        int row = wr * 64 + mt * 16 + (lane & 15);
        int kl = (kk * 32 + (lane >> 4) * 8) ^ ((row & 7) << 3);
        af[mt] = *reinterpret_cast<const s16x8*>(&lA[row * 64 + kl]);
      }
      #pragma unroll
      for (int nt = 0; nt < 4; ++nt) {
        int row = wc * 64 + nt * 16 + (lane & 15);
        int kl = (kk * 32 + (lane >> 4) * 8) ^ ((row & 7) << 3);
        bfr[nt] = *reinterpret_cast<const s16x8*>(&lB[row * 64 + kl]);
      }
      #pragma unroll
      for (int mt = 0; mt < 4; ++mt)
        #pragma unroll
        for (int nt = 0; nt < 4; ++nt)
          acc[mt][nt] = __builtin_amdgcn_mfma_f32_16x16x32_bf16(af[mt], bfr[nt], acc[mt][nt], 0, 0, 0);
    }
  }
  __syncthreads();
  const float NEG = -3.0e38f;
  #pragma unroll
  for (int nt = 0; nt < 4; ++nt) {
    int col_l = wc * 64 + nt * 16 + (lane & 15);
    int col = nh * 128 + col_l;
    float w40 = Wne_it[768 * 256 + col];
    float w41 = Wne_it[769 * 256 + col];
    float w42 = Wne_it[770 * 256 + col];
    float w43 = Wne_it[771 * 256 + col];
    float mx = NEG;
    #pragma unroll
    for (int mt = 0; mt < 4; ++mt)
      #pragma unroll
      for (int r = 0; r < 4; ++r) {
        int j = wr * 64 + mt * 16 + (lane >> 4) * 4 + r;
        float base = acc[mt][nt][r] + p.Q[j * 256 + col];
        float sej = se[j];
        float l0 = sl[j * 4 + 0], l1 = sl[j * 4 + 1];
        float l2 = sl[j * 4 + 2], l3 = sl[j * 4 + 3];
        if (sej > 0.f) {
          if (l0 > 0.f) mx = fmaxf(mx, base + l0 * w40);
          if (l1 > 0.f) mx = fmaxf(mx, base + l1 * w41);
          if (l2 > 0.f) mx = fmaxf(mx, base + l2 * w42);
          if (l3 > 0.f) mx = fmaxf(mx, base + l3 * w43);
        }
      }
    mx = fmaxf(mx, __shfl_xor(mx, 16));
    mx = fmaxf(mx, __shfl_xor(mx, 32));
    if (lane < 16) red[wr * 128 + col_l] = mx;
  }
  __syncthreads();
  if (tid < 128) {
    float m = fmaxf(red[tid], red[128 + tid]);
    float v = p.P[i * 256 + nh * 128 + tid] + m;   // P constant over (j,t): hoisted out of max
    cfn[i * 256 + nh * 128 + tid] = fmaxf(v, 0.f); // -inf + P -> 0 (empty mask case)
  }
}

__global__ __launch_bounds__(256) void mega(KParams p) {
  __shared__ __align__(16) char smem[40960];
  cg::grid_group grid = cg::this_grid();
  int bid = blockIdx.x, tid = threadIdx.x;

  // ---- S0: cf0 = relu(pf @ W_parent + b). 256 blocks x (32 f4-cols, 8 k-slices) ----
  {
    float* pfs = (float*)smem;                 // 282
    f32x4* red = (f32x4*)(smem + 2048);        // 256 f4
    pfs[tid] = p.p0[tid];
    if (tid < 16) pfs[256 + tid] = p.p1[tid];
    if (tid < 10) pfs[272 + tid] = p.p2[tid];
    __syncthreads();
    int cgi = tid & 31, s = tid >> 5;
    int colg = bid * 32 + cgi;                 // f4 column 0..8191
    const f32x4* W4 = (const f32x4*)p.Wp;
    int k0 = (s * 282) >> 3, k1e = ((s + 1) * 282) >> 3;
    f32x4 acc = {0.f, 0.f, 0.f, 0.f};
    #pragma unroll 4
    for (int k = k0; k < k1e; ++k)
      acc += pfs[k] * W4[(size_t)k * 8192 + colg];
    red[s * 32 + cgi] = acc;
    __syncthreads();
    if (tid < 32) {
      f32x4 v = red[tid];
      #pragma unroll
      for (int q = 1; q < 8; ++q) v += red[q * 32 + tid];
      v += ((const f32x4*)p.bp)[bid * 32 + tid];
      #pragma unroll
      for (int q = 0; q < 4; ++q) v[q] = fmaxf(v[q], 0.f);
      ((f32x4*)p.cf0)[bid * 32 + tid] = v;
    }
  }
  grid.sync();

  // ---- S1: A,B,P,Q matvecs + exists logits + W3T pack. Block (r, half) ----
  {
    int r = bid >> 1, half = bid & 1;
    float* c = (float*)smem;                   // 256
    float* redA = c + 256, *redB = redA + 256, *redP = redB + 256, *redQ = redP + 256;
    float* wsum = redQ + 256;                  // 4
    c[tid] = p.cf0[r * 256 + tid];
    __syncthreads();
    int cc = tid & 127, s = tid >> 7;
    int col = half * 128 + cc;
    const float* WelB = p.Wel + 256 * 256;
    float aA = 0.f, aB = 0.f, aP = 0.f, aQ = 0.f;
    #pragma unroll 4
    for (int kk = 0; kk < 128; ++kk) {
      int k = s * 128 + kk;
      float cv = c[k];
      aA += cv * p.Wel[k * 256 + col];
      aB += cv * WelB[k * 256 + col];
      aP += cv * p.Wne[k * 256 + col];
      aQ += cv * p.Wne[(256 + k) * 256 + col];
    }
    redA[tid] = aA; redB[tid] = aB; redP[tid] = aP; redQ[tid] = aQ;
    float v = (half == 0) ? c[tid] * p.Wex[tid] : 0.f;
    #pragma unroll
    for (int off = 32; off; off >>= 1) v += __shfl_xor(v, off);
    if ((tid & 63) == 0) wsum[tid >> 6] = v;
    __syncthreads();
    if (tid < 128) {
      int cl = half * 128 + tid;
      p.A[r * 256 + cl] = redA[tid] + redA[128 + tid];
      p.B[r * 256 + cl] = redB[tid] + redB[128 + tid];
      p.P[r * 256 + cl] = p.bne[cl] + redP[tid] + redP[128 + tid];
      p.Q[r * 256 + cl] = redQ[tid] + redQ[128 + tid];
    }
    if (half == 0 && tid == 0) {
      float lg = wsum[0] + wsum[1] + wsum[2] + wsum[3] + p.bex[0];
      p.out[40064 + r] = lg;
      p.ex0[r] = lg > 0.f ? 1.f : 0.f;
    }
    #pragma unroll
    for (int q = 0; q < 2; ++q) {              // pack W3 = Wne[it][512:768] -> bf16 [n][k^s]
      int idx = bid * 512 + q * 256 + tid;
      int it = idx >> 16, n = (idx >> 8) & 255, k = idx & 255;
      p.W3T[it * 65536 + n * 256 + (k ^ ((n & 7) << 3))] =
          f2bf(p.Wne[(size_t)(it * 772 + 512 + k) * 256 + n]);
    }
  }
  grid.sync();

  // ---- S2: EL + edge logits. Block (i, jh); two 32-j sub-tiles ----
  {
    int i = bid >> 1, jh = bid & 1;
    float* el = (float*)smem;                  // [32][257]
    float* wee = el + 32 * 257;                // [4][257]
    float a = p.A[i * 256 + tid] + p.bel[tid];
    #pragma unroll
    for (int t = 0; t < 4; ++t) wee[t * 257 + tid] = p.Wee[t * 256 + tid];
    for (int jq = 0; jq < 2; ++jq) {
      int jb = jh * 64 + jq * 32;
      __syncthreads();
      #pragma unroll 4
      for (int j = 0; j < 32; ++j) {
        float v = a + p.B[(jb + j) * 256 + tid];
        el[j * 257 + tid] = fmaxf(v, 0.f);
      }
      __syncthreads();
      // pack: thread (j2, cg8) writes 4 x short8 (swizzled global rows)
      int j2 = tid >> 3, cg8 = tid & 7;
      int pr = i * 128 + jb + j2;
      int sw = (pr & 7) << 3;
      #pragma unroll
      for (int q = 0; q < 4; ++q) {
        int c0 = cg8 * 32 + q * 8;
        s16x8 sv;
        #pragma unroll
        for (int e = 0; e < 8; ++e) sv[e] = (short)f2bf(el[j2 * 257 + c0 + e]);
        *reinterpret_cast<s16x8*>(p.ELbf + (size_t)pr * 256 + (c0 ^ sw)) = sv;
      }
      // logits: thread (j3, t, chalf); fp32
      int j3 = tid >> 3, t = (tid >> 1) & 3, ch = tid & 1;
      float accl = 0.f;
      #pragma unroll 4
      for (int k = 0; k < 128; ++k)
        accl += el[j3 * 257 + ch * 128 + k] * wee[t * 257 + ch * 128 + k];
      accl += __shfl_xor(accl, 1);
      if (ch == 0) p.out[40192 + (i * 128 + jb + j3) * 4 + t] = accl + p.bee[t];
    }
  }
  grid.sync();

  // ---- S3: fused GEMM+scatter (it 0) -> cf1 ----
  kf_stage(p, p.W3T, p.Wne, p.cf1, smem, bid, tid);
  grid.sync();

  // ---- S4: P,Q for it 1 from cf1 ----
  {
    int r = bid >> 1, half = bid & 1;
    float* c = (float*)smem;
    float* redP = c + 256, *redQ = redP + 256;
    c[tid] = p.cf1[r * 256 + tid];
    __syncthreads();
    int cc = tid & 127, s = tid >> 7;
    int col = half * 128 + cc;
    const float* Wn = p.Wne + 772 * 256;
    float aP = 0.f, aQ = 0.f;
    #pragma unroll 4
    for (int kk = 0; kk < 128; ++kk) {
      int k = s * 128 + kk;
      float cv = c[k];
      aP += cv * Wn[k * 256 + col];
      aQ += cv * Wn[(256 + k) * 256 + col];
    }
    redP[tid] = aP; redQ[tid] = aQ;
    __syncthreads();
    if (tid < 128) {
      int cl = half * 128 + tid;
      p.P[r * 256 + cl] = p.bne[256 + cl] + redP[tid] + redP[128 + tid];
      p.Q[r * 256 + cl] = redQ[tid] + redQ[128 + tid];
    }
  }
  grid.sync();

  // ---- S5: fused GEMM+scatter (it 1) -> cf2 ----
  kf_stage(p, p.W3T + 65536, p.Wne + 772 * 256, p.cf2, smem, bid, tid);
  grid.sync();

  // ---- S6: h = relu([cf0|cf1|cf2] @ W_child + bc) ----
  {
    int m = bid >> 1, half = bid & 1;
    float* af = (float*)smem;                  // 768
    float* red = af + 768;                     // 256
    af[tid] = p.cf0[m * 256 + tid];
    af[256 + tid] = p.cf1[m * 256 + tid];
    af[512 + tid] = p.cf2[m * 256 + tid];
    __syncthreads();
    int cc = tid & 127, s = tid >> 7;
    int col = half * 128 + cc;
    float acc = 0.f;
    #pragma unroll 4
    for (int kk = 0; kk < 384; ++kk) {
      int k = s * 384 + kk;
      acc += af[k] * p.Wc[k * 256 + col];
    }
    red[tid] = acc;
    __syncthreads();
    if (tid < 128) {
      float v = p.bc[half * 128 + tid] + red[tid] + red[128 + tid];
      p.hws[m * 256 + half * 128 + tid] = fmaxf(v, 0.f);
    }
  }
  grid.sync();

  // ---- S7: out_co + sem ----
  {
    int m = bid >> 1, half = bid & 1;
    float* hb = (float*)smem;                  // 256
    float* red = hb + 256;                     // 256
    float* redS = red + 256;                   // 228
    hb[tid] = p.hws[m * 256 + tid];
    __syncthreads();
    int cc = tid & 127, s = tid >> 7;
    int col = half * 128 + cc;
    float acc = 0.f;
    #pragma unroll 4
    for (int kk = 0; kk < 128; ++kk) {
      int k = s * 128 + kk;
      acc += hb[k] * p.W2[k * 256 + col];
    }
    red[tid] = acc;
    int c57 = tid & 63, s4 = tid >> 6;
    if (half == 0 && c57 < 57) {
      float accs = 0.f;
      #pragma unroll 4
      for (int kk = 0; kk < 64; ++kk) {
        int k = s4 * 64 + kk;
        accs += hb[k] * p.Wsm[k * 57 + c57];
      }
      redS[s4 * 57 + c57] = accs;
    }
    __syncthreads();
    if (tid < 128) {
      float v = p.b2[half * 128 + tid] + red[tid] + red[128 + tid];
      p.out[m * 256 + half * 128 + tid] = fmaxf(v, 0.f);
    }
    if (half == 0 && tid < 57) {
      float v = p.bsm[tid] + redS[tid] + redS[57 + tid] + redS[114 + tid] + redS[171 + tid];
      p.out[32768 + m * 57 + tid] = v;
    }
  }
}

extern "C" void kernel_launch(void* const* d_in, const int* in_sizes, int n_in,
                              void* d_out, int out_size, void* d_ws, size_t ws_size,
                              hipStream_t stream) {
  KParams prm;
  prm.p0  = (const float*)d_in[0];
  prm.p1  = (const float*)d_in[1];
  prm.p2  = (const float*)d_in[2];
  prm.Wp  = (const float*)d_in[3];
  prm.bp  = (const float*)d_in[4];
  prm.Wex = (const float*)d_in[5];
  prm.bex = (const float*)d_in[6];
  prm.Wsm = (const float*)d_in[7];
  prm.bsm = (const float*)d_in[8];
  prm.Wel = (const float*)d_in[9];
  prm.bel = (const float*)d_in[10];
  prm.Wee = (const float*)d_in[11];
  prm.bee = (const float*)d_in[12];
  prm.Wne = (const float*)d_in[13];
  prm.bne = (const float*)d_in[14];
  prm.Wc  = (const float*)d_in[15];
  prm.bc  = (const float*)d_in[16];
  prm.W2  = (const float*)d_in[17];
  prm.b2  = (const float*)d_in[18];
  prm.out = (float*)d_out;

  char* ws = (char*)d_ws;
  prm.cf0  = (float*)(ws + 0);
  prm.cf1  = (float*)(ws + 131072);
  prm.cf2  = (float*)(ws + 262144);
  prm.A    = (float*)(ws + 393216);
  prm.B    = (float*)(ws + 524288);
  prm.P    = (float*)(ws + 655360);
  prm.Q    = (float*)(ws + 786432);
  prm.ex0  = (float*)(ws + 917504);
  prm.hws  = (float*)(ws + 918528);
  prm.W3T  = (ushort_t*)(ws + 1048576);
  prm.ELbf = (ushort_t*)(ws + 2097152);

  void* args[] = { &prm };
  hipLaunchCooperativeKernel((const void*)mega, dim3(256), dim3(256), args, 0, stream);
}

// Round 6
// 216.434 us; speedup vs baseline: 2.0576x; 2.0576x over previous
//
#include <hip/hip_runtime.h>
#include <hip/hip_bf16.h>
#include <stdint.h>

// RecursiveDecoder. M=128, H=F=256, T=4, ITERS=2, NSEM=57.
// R5 lesson: cooperative grid.sync() costs ~40-50us each on MI355X (cross-XCD
// barrier + 1 block/CU cap) -> mega-kernel was 350us. Back to 7 stream-ordered
// kernels, keeping all barrier-free fusions:
//   k1   cf0 = relu(pf @ W_parent + b)            [37 MB, HBM-bound, 16 waves/CU]
//   ks1  A,B = cf0@W_el | P,Q = cf0@Wne0 | exists logits | W3T bf16 pack
//   k3   EL = relu(A[i]+B[j]+bel) -> ELbf (bf16 swizzled) + edge logits (fp32)
//   kf   it0: ELbf@W3 via MFMA + fused masked scatter-max -> cf1 (R never materialized)
//   kp1  P,Q = cf1@Wne1
//   kf   it1 -> cf2
//   k6   h = relu([cf0|cf1|cf2]@Wc+bc) in LDS; out_co = relu(h@W2+b2); sem = h@Wsem+bsem
// Mask-critical values (exists/edge logits) stay fp32; only EL->R path is bf16 MFMA.
// ws: cf0 0 | cf1 128K | cf2 256K | A 384K | B 512K | P 640K | Q 768K | ex0 896K |
//     W3T 1M (256K) | ELbf 2M (8M)

typedef unsigned short ushort_t;
using f32x4 = __attribute__((ext_vector_type(4))) float;
using s16x8 = __attribute__((ext_vector_type(8))) short;

__device__ __forceinline__ ushort_t f2bf(float x) {
  __hip_bfloat16 h = __float2bfloat16(x);
  return *reinterpret_cast<ushort_t*>(&h);
}

// ---------- k1: cf0 = relu(pf @ W_parent + b). 1024 blocks x (8 f4-cols, 32 k-slices) ----------
__global__ __launch_bounds__(256) void k1_parent(
    const float* __restrict__ p0, const float* __restrict__ p1, const float* __restrict__ p2,
    const float* __restrict__ W, const float* __restrict__ b, float* __restrict__ cf) {
  __shared__ float pfs[282];
  __shared__ f32x4 red[320];                    // 256 + 64
  int tid = threadIdx.x;
  pfs[tid] = p0[tid];
  if (tid < 16) pfs[256 + tid] = p1[tid];
  if (tid < 10) pfs[272 + tid] = p2[tid];
  __syncthreads();
  int c = tid & 7, s = tid >> 3;               // 32 k-slices of ~9
  int colg = blockIdx.x * 8 + c;               // f4 column 0..8191
  const f32x4* W4 = (const f32x4*)W;
  int k0 = (s * 282) >> 5, k1e = ((s + 1) * 282) >> 5;
  f32x4 acc = {0.f, 0.f, 0.f, 0.f};
  #pragma unroll 4
  for (int k = k0; k < k1e; ++k)
    acc += pfs[k] * W4[(size_t)k * 8192 + colg];
  red[s * 8 + c] = acc;
  __syncthreads();
  if (tid < 64) {
    int col = tid & 7, part = tid >> 3;        // 8 parts x 4 slices
    f32x4 v = red[(part * 4 + 0) * 8 + col] + red[(part * 4 + 1) * 8 + col]
            + red[(part * 4 + 2) * 8 + col] + red[(part * 4 + 3) * 8 + col];
    red[256 + part * 8 + col] = v;
  }
  __syncthreads();
  if (tid < 8) {
    f32x4 v = red[256 + tid];
    #pragma unroll
    for (int q = 1; q < 8; ++q) v += red[256 + q * 8 + tid];
    v += ((const f32x4*)b)[blockIdx.x * 8 + tid];
    #pragma unroll
    for (int q = 0; q < 4; ++q) v[q] = fmaxf(v[q], 0.f);
    ((f32x4*)cf)[blockIdx.x * 8 + tid] = v;
  }
}

// ---------- ks1: A,B,P,Q matvecs + exists logits + W3T pack. 256 blocks x 1024 thr ----------
__global__ __launch_bounds__(1024) void ks1(
    const float* __restrict__ cf, const float* __restrict__ Wel,
    const float* __restrict__ Wne, const float* __restrict__ bne,
    const float* __restrict__ Wex, const float* __restrict__ bex,
    float* __restrict__ A, float* __restrict__ B, float* __restrict__ P,
    float* __restrict__ Q, float* __restrict__ ex0, float* __restrict__ exout,
    ushort_t* __restrict__ W3T) {
  __shared__ float c[256];
  __shared__ float redA[1024], redB[1024], redP[1024], redQ[1024];
  __shared__ float wsum[4];
  int tid = threadIdx.x;
  int r = blockIdx.x >> 1, half = blockIdx.x & 1;
  if (tid < 256) c[tid] = cf[r * 256 + tid];
  __syncthreads();
  int cc = tid & 127, s = tid >> 7;            // 8 k-slices of 32
  int col = half * 128 + cc;
  int k0 = s * 32;
  const float* WelB = Wel + 256 * 256;
  float aA = 0.f, aB = 0.f, aP = 0.f, aQ = 0.f;
  #pragma unroll 4
  for (int kk = 0; kk < 32; ++kk) {
    int k = k0 + kk;
    float cv = c[k];
    aA += cv * Wel[k * 256 + col];
    aB += cv * WelB[k * 256 + col];
    aP += cv * Wne[k * 256 + col];
    aQ += cv * Wne[(256 + k) * 256 + col];
  }
  redA[tid] = aA; redB[tid] = aB; redP[tid] = aP; redQ[tid] = aQ;
  float v = (half == 0 && tid < 256) ? c[tid] * Wex[tid] : 0.f;
  #pragma unroll
  for (int off = 32; off; off >>= 1) v += __shfl_xor(v, off);
  if (half == 0 && tid < 256 && (tid & 63) == 0) wsum[tid >> 6] = v;
  __syncthreads();
  if (tid < 128) {
    int cl = half * 128 + tid;
    float a = 0.f, bb = 0.f, pv = bne[cl], qv = 0.f;
    #pragma unroll
    for (int q = 0; q < 8; ++q) {
      a  += redA[q * 128 + tid];
      bb += redB[q * 128 + tid];
      pv += redP[q * 128 + tid];
      qv += redQ[q * 128 + tid];
    }
    A[r * 256 + cl] = a;
    B[r * 256 + cl] = bb;
    P[r * 256 + cl] = pv;
    Q[r * 256 + cl] = qv;
  }
  if (half == 0 && tid == 0) {
    float lg = wsum[0] + wsum[1] + wsum[2] + wsum[3] + bex[0];
    exout[r] = lg;
    ex0[r] = lg > 0.f ? 1.f : 0.f;
  }
  if (tid < 512) {                             // pack W3 = Wne[it][512:768] -> bf16 [n][k^s]
    int idx = blockIdx.x * 512 + tid;          // 131072 total
    int it = idx >> 16, n = (idx >> 8) & 255, k = idx & 255;
    W3T[it * 65536 + n * 256 + (k ^ ((n & 7) << 3))] =
        f2bf(Wne[(size_t)(it * 772 + 512 + k) * 256 + n]);
  }
}

// ---------- k3: EL + edge logits, 4 pairs per block. 4096 blocks x 256 ----------
__global__ __launch_bounds__(256) void k3_edge(
    const float* __restrict__ A, const float* __restrict__ B, const float* __restrict__ bel,
    const float* __restrict__ Wee, const float* __restrict__ bee,
    ushort_t* __restrict__ ELbf, float* __restrict__ elog) {
  __shared__ float w4s[4][4][4];               // [jj][wid][t]
  int tid = threadIdx.x, lane = tid & 63, wid = tid >> 6;
  int p0 = blockIdx.x * 4;
  int i = p0 >> 7;                             // same i for all 4 pairs (4 | 128)
  float a = A[i * 256 + tid] + bel[tid];
  float we0 = Wee[tid], we1 = Wee[256 + tid], we2 = Wee[512 + tid], we3 = Wee[768 + tid];
  #pragma unroll
  for (int jj = 0; jj < 4; ++jj) {
    int pr = p0 + jj;
    int j = pr & 127;
    float el = fmaxf(a + B[j * 256 + tid], 0.f);
    ELbf[(size_t)pr * 256 + (tid ^ ((pr & 7) << 3))] = f2bf(el);
    float t0 = el * we0, t1 = el * we1, t2 = el * we2, t3 = el * we3;
    #pragma unroll
    for (int off = 32; off; off >>= 1) {
      t0 += __shfl_xor(t0, off);
      t1 += __shfl_xor(t1, off);
      t2 += __shfl_xor(t2, off);
      t3 += __shfl_xor(t3, off);
    }
    if (lane == 0) { w4s[jj][wid][0] = t0; w4s[jj][wid][1] = t1;
                     w4s[jj][wid][2] = t2; w4s[jj][wid][3] = t3; }
  }
  __syncthreads();
  if (tid < 16) {
    int jj = tid >> 2, t = tid & 3;
    float v = w4s[jj][0][t] + w4s[jj][1][t] + w4s[jj][2][t] + w4s[jj][3][t] + bee[t];
    elog[(p0 + jj) * 4 + t] = v;
  }
}

// ---------- kf: fused GEMM(128x256 @ 256x128, bf16 MFMA) + masked scatter-max ----------
__global__ __launch_bounds__(256) void kf(
    const ushort_t* __restrict__ ELbf, const ushort_t* __restrict__ W3T_it,
    const float* __restrict__ Wne_it, const float* __restrict__ P,
    const float* __restrict__ Q, const float* __restrict__ ex0,
    const float* __restrict__ elog, float* __restrict__ cfn) {
  __shared__ __align__(16) ushort_t lA[128 * 64];
  __shared__ __align__(16) ushort_t lB[128 * 64];
  __shared__ float sl[512];
  __shared__ float se[128];
  __shared__ float red[256];
  int tid = threadIdx.x;
  int i = blockIdx.x >> 1, nh = blockIdx.x & 1;
  if (ex0[i] == 0.f) {                         // block-uniform
    if (tid < 128) cfn[i * 256 + nh * 128 + tid] = 0.f;
    return;
  }
  sl[tid] = elog[i * 512 + tid];
  sl[256 + tid] = elog[i * 512 + 256 + tid];
  if (tid < 128) se[tid] = ex0[tid];
  int lane = tid & 63, wid = tid >> 6;
  int wr = wid >> 1, wc = wid & 1;
  f32x4 acc[4][4] = {};
  for (int ks = 0; ks < 256; ks += 64) {
    __syncthreads();
    #pragma unroll
    for (int rr = 0; rr < 4; ++rr) {
      int c = rr * 4 + wid;                    // wave-uniform chunk 0..15
      int row = c * 8 + (lane >> 3);
      int co = (lane & 7) * 8;
      const ushort_t* sa = ELbf + (size_t)(i * 128 + row) * 256 + ks + co;
      const ushort_t* sb = W3T_it + (size_t)(nh * 128 + row) * 256 + ks + co;
      __builtin_amdgcn_global_load_lds((const __attribute__((address_space(1))) void*)sa,
                                       (__attribute__((address_space(3))) void*)(lA + c * 512), 16, 0, 0);
      __builtin_amdgcn_global_load_lds((const __attribute__((address_space(1))) void*)sb,
                                       (__attribute__((address_space(3))) void*)(lB + c * 512), 16, 0, 0);
    }
    __syncthreads();
    #pragma unroll
    for (int kk = 0; kk < 2; ++kk) {
      s16x8 af[4], bfr[4];
      #pragma unroll
      for (int mt = 0; mt < 4; ++mt) {
        int row = wr * 64 + mt * 16 + (lane & 15);
        int kl = (kk * 32 + (lane >> 4) * 8) ^ ((row & 7) << 3);
        af[mt] = *reinterpret_cast<const s16x8*>(&lA[row * 64 + kl]);
      }
      #pragma unroll
      for (int nt = 0; nt < 4; ++nt) {
        int row = wc * 64 + nt * 16 + (lane & 15);
        int kl = (kk * 32 + (lane >> 4) * 8) ^ ((row & 7) << 3);
        bfr[nt] = *reinterpret_cast<const s16x8*>(&lB[row * 64 + kl]);
      }
      #pragma unroll
      for (int mt = 0; mt < 4; ++mt)
        #pragma unroll
        for (int nt = 0; nt < 4; ++nt)
          acc[mt][nt] = __builtin_amdgcn_mfma_f32_16x16x32_bf16(af[mt], bfr[nt], acc[mt][nt], 0, 0, 0);
    }
  }
  __syncthreads();
  const float NEG = -3.0e38f;
  #pragma unroll
  for (int nt = 0; nt < 4; ++nt) {
    int col_l = wc * 64 + nt * 16 + (lane & 15);
    int col = nh * 128 + col_l;
    float w40 = Wne_it[768 * 256 + col];
    float w41 = Wne_it[769 * 256 + col];
    float w42 = Wne_it[770 * 256 + col];
    float w43 = Wne_it[771 * 256 + col];
    float mx = NEG;
    #pragma unroll
    for (int mt = 0; mt < 4; ++mt)
      #pragma unroll
      for (int r = 0; r < 4; ++r) {
        int j = wr * 64 + mt * 16 + (lane >> 4) * 4 + r;
        float base = acc[mt][nt][r] + Q[j * 256 + col];
        float sej = se[j];
        float l0 = sl[j * 4 + 0], l1 = sl[j * 4 + 1];
        float l2 = sl[j * 4 + 2], l3 = sl[j * 4 + 3];
        if (sej > 0.f) {
          if (l0 > 0.f) mx = fmaxf(mx, base + l0 * w40);
          if (l1 > 0.f) mx = fmaxf(mx, base + l1 * w41);
          if (l2 > 0.f) mx = fmaxf(mx, base + l2 * w42);
          if (l3 > 0.f) mx = fmaxf(mx, base + l3 * w43);
        }
      }
    mx = fmaxf(mx, __shfl_xor(mx, 16));
    mx = fmaxf(mx, __shfl_xor(mx, 32));
    if (lane < 16) red[wr * 128 + col_l] = mx;
  }
  __syncthreads();
  if (tid < 128) {
    float m = fmaxf(red[tid], red[128 + tid]);
    float v = P[i * 256 + nh * 128 + tid] + m;     // P constant over (j,t)
    cfn[i * 256 + nh * 128 + tid] = fmaxf(v, 0.f); // -inf + P -> 0 (empty mask)
  }
}

// ---------- kp1: P,Q for iter 1 from cf1. 256 blocks x 1024 ----------
__global__ __launch_bounds__(1024) void kp1(
    const float* __restrict__ cf, const float* __restrict__ Wne_it,
    const float* __restrict__ bne_it, float* __restrict__ P, float* __restrict__ Q) {
  __shared__ float c[256];
  __shared__ float redP[1024], redQ[1024];
  int tid = threadIdx.x;
  int r = blockIdx.x >> 1, half = blockIdx.x & 1;
  if (tid < 256) c[tid] = cf[r * 256 + tid];
  __syncthreads();
  int cc = tid & 127, s = tid >> 7;
  int col = half * 128 + cc;
  int k0 = s * 32;
  float aP = 0.f, aQ = 0.f;
  #pragma unroll 4
  for (int kk = 0; kk < 32; ++kk) {
    int k = k0 + kk;
    float cv = c[k];
    aP += cv * Wne_it[k * 256 + col];
    aQ += cv * Wne_it[(256 + k) * 256 + col];
  }
  redP[tid] = aP; redQ[tid] = aQ;
  __syncthreads();
  if (tid < 128) {
    int cl = half * 128 + tid;
    float pv = bne_it[cl], qv = 0.f;
    #pragma unroll
    for (int q = 0; q < 8; ++q) { pv += redP[q * 128 + tid]; qv += redQ[q * 128 + tid]; }
    P[r * 256 + cl] = pv;
    Q[r * 256 + cl] = qv;
  }
}

// ---------- k6: fused final. 128 blocks (row m) x 1024 thr; h lives in LDS ----------
__global__ __launch_bounds__(1024) void k6_final(
    const float* __restrict__ cf0, const float* __restrict__ cf1, const float* __restrict__ cf2,
    const float* __restrict__ Wc, const float* __restrict__ bc,
    const float* __restrict__ Wsem, const float* __restrict__ bsem,
    const float* __restrict__ W2, const float* __restrict__ b2,
    float* __restrict__ out) {
  __shared__ float af[768];
  __shared__ float red[1024];
  __shared__ float hb[256];
  __shared__ float redS[4 * 57];
  int tid = threadIdx.x, m = blockIdx.x;
  if (tid < 768) {
    af[tid] = tid < 256 ? cf0[m * 256 + tid]
            : tid < 512 ? cf1[m * 256 + tid - 256]
                        : cf2[m * 256 + tid - 512];
  }
  __syncthreads();
  int cc = tid & 255, s = tid >> 8;            // 4 k-slices of 192
  {
    float acc = 0.f;
    #pragma unroll 4
    for (int kk = 0; kk < 192; ++kk) {
      int k = s * 192 + kk;
      acc += af[k] * Wc[k * 256 + cc];
    }
    red[tid] = acc;
  }
  __syncthreads();
  if (tid < 256) {
    float v = bc[tid] + red[tid] + red[256 + tid] + red[512 + tid] + red[768 + tid];
    hb[tid] = fmaxf(v, 0.f);
  }
  __syncthreads();
  {
    float acc = 0.f;                           // out_co: 4 k-slices of 64
    #pragma unroll 4
    for (int kk = 0; kk < 64; ++kk) {
      int k = s * 64 + kk;
      acc += hb[k] * W2[k * 256 + cc];
    }
    red[tid] = acc;
    if (cc < 57) {
      float accs = 0.f;
      #pragma unroll 4
      for (int kk = 0; kk < 64; ++kk) {
        int k = s * 64 + kk;
        accs += hb[k] * Wsem[k * 57 + cc];
      }
      redS[s * 57 + cc] = accs;
    }
  }
  __syncthreads();
  if (tid < 256) {
    float v = b2[tid] + red[tid] + red[256 + tid] + red[512 + tid] + red[768 + tid];
    out[m * 256 + tid] = fmaxf(v, 0.f);
  }
  if (tid < 57) {
    float v = bsem[tid] + redS[tid] + redS[57 + tid] + redS[114 + tid] + redS[171 + tid];
    out[32768 + m * 57 + tid] = v;
  }
}

extern "C" void kernel_launch(void* const* d_in, const int* in_sizes, int n_in,
                              void* d_out, int out_size, void* d_ws, size_t ws_size,
                              hipStream_t stream) {
  const float* p0  = (const float*)d_in[0];
  const float* p1  = (const float*)d_in[1];
  const float* p2  = (const float*)d_in[2];
  const float* Wp  = (const float*)d_in[3];
  const float* bp  = (const float*)d_in[4];
  const float* Wex = (const float*)d_in[5];
  const float* bex = (const float*)d_in[6];
  const float* Wsm = (const float*)d_in[7];
  const float* bsm = (const float*)d_in[8];
  const float* Wel = (const float*)d_in[9];
  const float* bel = (const float*)d_in[10];
  const float* Wee = (const float*)d_in[11];
  const float* bee = (const float*)d_in[12];
  const float* Wne = (const float*)d_in[13];
  const float* bne = (const float*)d_in[14];
  const float* Wc  = (const float*)d_in[15];
  const float* bc  = (const float*)d_in[16];
  const float* W2  = (const float*)d_in[17];
  const float* b2  = (const float*)d_in[18];
  float* out = (float*)d_out;

  char* ws = (char*)d_ws;
  float*    cf0  = (float*)(ws + 0);
  float*    cf1  = (float*)(ws + 131072);
  float*    cf2  = (float*)(ws + 262144);
  float*    Ab   = (float*)(ws + 393216);
  float*    Bb   = (float*)(ws + 524288);
  float*    Pb   = (float*)(ws + 655360);
  float*    Qb   = (float*)(ws + 786432);
  float*    ex0  = (float*)(ws + 917504);
  ushort_t* W3T  = (ushort_t*)(ws + 1048576);  // 256K
  ushort_t* ELbf = (ushort_t*)(ws + 2097152);  // 8M

  float* out_ex = out + 40064;                 // [128]
  float* out_el = out + 40192;                 // [128,128,4]

  k1_parent<<<1024, 256, 0, stream>>>(p0, p1, p2, Wp, bp, cf0);
  ks1<<<256, 1024, 0, stream>>>(cf0, Wel, Wne, bne, Wex, bex,
                                Ab, Bb, Pb, Qb, ex0, out_ex, W3T);
  k3_edge<<<4096, 256, 0, stream>>>(Ab, Bb, bel, Wee, bee, ELbf, out_el);
  kf<<<256, 256, 0, stream>>>(ELbf, W3T, Wne, Pb, Qb, ex0, out_el, cf1);
  kp1<<<256, 1024, 0, stream>>>(cf1, Wne + 772 * 256, bne + 256, Pb, Qb);
  kf<<<256, 256, 0, stream>>>(ELbf, W3T + 65536, Wne + 772 * 256, Pb, Qb, ex0, out_el, cf2);
  k6_final<<<128, 1024, 0, stream>>>(cf0, cf1, cf2, Wc, bc, Wsm, bsm, W2, b2, out);
}